// Round 10
// baseline (805.285 us; speedup 1.0000x reference)
//
#include <hip/hip_runtime.h>
#include <hip/hip_bf16.h>
#include <hip/hip_fp16.h>

#define LEAKY_ATT 0.2f
#define LEAKY_ACT 0.01f
#define BSHIFT 8
#define CH 4096

typedef __attribute__((ext_vector_type(8))) short bf16x8;
typedef __attribute__((ext_vector_type(4))) float f32x4;

__device__ __forceinline__ float lrelu(float x, float s) { return fmaxf(x, s * x); }

__device__ __forceinline__ uint f2bf(float f) {
  __hip_bfloat16 h = __float2bfloat16(f);  // RTNE
  return (uint)*reinterpret_cast<ushort*>(&h);
}

__device__ __forceinline__ float bf_lo(uint q) { return __uint_as_float(q << 16); }
__device__ __forceinline__ float bf_hi(uint q) { return __uint_as_float(q & 0xffff0000u); }

__device__ __forceinline__ ushort f2h(float f) {
  __half h = __float2half(f);
  return *reinterpret_cast<ushort*>(&h);
}
__device__ __forceinline__ float h2f(ushort u) {
  __half h = *reinterpret_cast<__half*>(&u);
  return __half2float(h);
}

// ============================ CSR build: two-level counting sort ============================
__global__ __launch_bounds__(256) void k_bhist(const int* __restrict__ dst, int e, int nb,
                                               int* __restrict__ bcnt) {
  __shared__ int cnt[512];
  for (int i = threadIdx.x; i < 512; i += 256) cnt[i] = 0;
  __syncthreads();
  for (int i = blockIdx.x * 256 + threadIdx.x; i < e; i += gridDim.x * 256)
    atomicAdd(&cnt[dst[i] >> BSHIFT], 1);
  __syncthreads();
  for (int i = threadIdx.x; i < nb; i += 256)
    if (cnt[i]) atomicAdd(&bcnt[i], cnt[i]);
}

__global__ __launch_bounds__(512) void k_bscan(const int* __restrict__ bcnt, int nb,
                                               int* __restrict__ bbase, int* __restrict__ bcur) {
  __shared__ int sh[512];
  int t = threadIdx.x;
  int orig = (t < nb) ? bcnt[t] : 0;
  sh[t] = orig;
  __syncthreads();
  for (int off = 1; off < 512; off <<= 1) {
    int v = (t >= off) ? sh[t - off] : 0;
    __syncthreads();
    sh[t] += v;
    __syncthreads();
  }
  if (t < nb) {
    int ex = sh[t] - orig;
    bbase[t] = ex;
    bcur[t] = ex;
    if (t == nb - 1) bbase[nb] = sh[t];
  }
}

__global__ __launch_bounds__(256) void k_bucket(const int* __restrict__ src,
                                                const int* __restrict__ dst, int e, int nb,
                                                int* __restrict__ bcur, uint* __restrict__ bpair) {
  __shared__ uint spair[CH];
  __shared__ ushort skey[CH];
  __shared__ ushort srank[CH];
  __shared__ int cnt[512];
  __shared__ int gb[512];
  int t = threadIdx.x;
  int c0 = blockIdx.x * CH;
  int cn = min(CH, e - c0);
  if (cn <= 0) return;
  for (int i = t; i < 512; i += 256) cnt[i] = 0;
  __syncthreads();
  for (int i = t; i < cn; i += 256) {
    int s = src[c0 + i];
    int d = dst[c0 + i];
    int k = d >> BSHIFT;
    spair[i] = ((uint)(d & ((1 << BSHIFT) - 1)) << 20) | (uint)s;
    skey[i] = (ushort)k;
    srank[i] = (ushort)atomicAdd(&cnt[k], 1);
  }
  __syncthreads();
  for (int k = t; k < nb; k += 256)
    gb[k] = cnt[k] ? atomicAdd(&bcur[k], cnt[k]) : 0;
  __syncthreads();
  for (int i = t; i < cn; i += 256) {
    bpair[gb[skey[i]] + srank[i]] = spair[i];
  }
}

__global__ __launch_bounds__(256) void k_csr(const uint* __restrict__ bpair,
                                             const int* __restrict__ bbase, int n,
                                             int* __restrict__ rowptr, int* __restrict__ col) {
  __shared__ int deg[256];
  __shared__ int cur[256];
  int b = blockIdx.x, t = threadIdx.x;
  int e0 = bbase[b], e1 = bbase[b + 1];
  deg[t] = 0;
  __syncthreads();
  for (int i = e0 + t; i < e1; i += 256)
    atomicAdd(&deg[bpair[i] >> 20], 1);
  __syncthreads();
  int v = deg[t];
  cur[t] = v;
  __syncthreads();
  for (int off = 1; off < 256; off <<= 1) {
    int u = (t >= off) ? cur[t - off] : 0;
    __syncthreads();
    cur[t] += u;
    __syncthreads();
  }
  int incl = cur[t];
  int gnode = b * 256 + t;
  if (gnode < n) rowptr[gnode + 1] = e0 + incl;
  if (b == 0 && t == 0) rowptr[0] = 0;
  __syncthreads();
  cur[t] = e0 + incl - v;
  __syncthreads();
  for (int i = e0 + t; i < e1; i += 256) {
    uint pk = bpair[i];
    int loc = pk >> 20;
    int p = atomicAdd(&cur[loc], 1);
    col[p] = (int)(pk & 0xFFFFFu);
  }
}

// ============================ weight prep ============================
__global__ void k_prep_vsd(const float* __restrict__ wsrc, const float* __restrict__ wdst,
                           const float* __restrict__ asrc, const float* __restrict__ adst,
                           float* __restrict__ vsd) {
  int k = blockIdx.x;
  int i = threadIdx.x;
  float s = 0.f;
  if (i < 8) {
    for (int c = 0; c < 16; ++c) s += wsrc[k * 128 + i * 16 + c] * asrc[i * 16 + c];
  } else {
    int h = i - 8;
    for (int c = 0; c < 16; ++c) s += wdst[k * 128 + h * 16 + c] * adst[h * 16 + c];
  }
  vsd[k * 16 + i] = s;
}

__global__ void k_prep_u3(const float* __restrict__ w3s, const float* __restrict__ w3d,
                          const float* __restrict__ a3s, const float* __restrict__ a3d,
                          float* __restrict__ U) {
  int k = blockIdx.x * blockDim.x + threadIdx.x;
  if (k >= 128) return;
  U[k * 4 + 0] = w3s[k * 2 + 0];
  U[k * 4 + 1] = w3s[k * 2 + 1];
  U[k * 4 + 2] = w3s[k * 2 + 0] * a3s[0] + w3s[k * 2 + 1] * a3s[1];
  U[k * 4 + 3] = w3d[k * 2 + 0] * a3d[0] + w3d[k * 2 + 1] * a3d[1];
}

// B-fragment pre-swizzle (see R6 notes)
__global__ __launch_bounds__(64) void k_prep_frag(const float* __restrict__ W,
                                                  const float* __restrict__ VSD,
                                                  ushort* __restrict__ WF) {
  int blk = blockIdx.x;  // ct*4+ks, 36 blocks
  int lane = threadIdx.x;
  int ct = blk >> 2, ks = blk & 3;
  uint out[4];
#pragma unroll
  for (int jj = 0; jj < 8; ++jj) {
    int k = ks * 32 + (lane >> 4) * 8 + jj;
    int c = ct * 16 + (lane & 15);
    float v = (c < 128) ? W[k * 128 + c] : VSD[k * 16 + (c - 128)];
    ((ushort*)out)[jj] = (ushort)f2bf(v);
  }
  *reinterpret_cast<uint4*>(&WF[(size_t)(blk * 64 + lane) * 8]) = *reinterpret_cast<uint4*>(out);
}

// ============================ MFMA GEMM: [XSH | ALS/ALD] = Xtile @ [W | VSD] ============================
// XSH head-major: XSH[h][node][16] bf16. ALS/ALD: [node][8] f32 rows.
template <int INMODE>  // 0: fp32 X, 1: bf16 X
__global__ __launch_bounds__(256) void k_gemm_mfma(const void* __restrict__ Xv,
                                                   const ushort* __restrict__ WF,
                                                   ushort* __restrict__ XSH,
                                                   float* __restrict__ ALS,
                                                   float* __restrict__ ALD, int n) {
  __shared__ __align__(16) char xt[16384];  // 64 rows x 128 k bf16
  int t = threadIdx.x;
  int row0 = blockIdx.x * 64;

  if (INMODE == 0) {
    const float* X = (const float*)Xv;
#pragma unroll
    for (int i = 0; i < 8; ++i) {
      int flat = (i * 256 + t) * 4;
      int r = flat >> 7, k0 = flat & 127;
      int gr = row0 + r;
      float4 v = (gr < n) ? *reinterpret_cast<const float4*>(&X[(size_t)gr * 128 + k0])
                          : make_float4(0.f, 0.f, 0.f, 0.f);
      uint lo = f2bf(v.x) | (f2bf(v.y) << 16);
      uint hi = f2bf(v.z) | (f2bf(v.w) << 16);
      int byte = (r * 256 + k0 * 2) ^ ((r & 7) << 4);
      *reinterpret_cast<uint2*>(xt + byte) = make_uint2(lo, hi);
    }
  } else {
    const ushort* X = (const ushort*)Xv;
#pragma unroll
    for (int i = 0; i < 4; ++i) {
      int flat = (i * 256 + t) * 8;
      int r = flat >> 7, k0 = flat & 127;
      int gr = row0 + r;
      uint4 v = (gr < n) ? *reinterpret_cast<const uint4*>(&X[(size_t)gr * 128 + k0])
                         : make_uint4(0u, 0u, 0u, 0u);
      int byte = (r * 256 + k0 * 2) ^ ((r & 7) << 4);
      *reinterpret_cast<uint4*>(xt + byte) = v;
    }
  }
  __syncthreads();

  int wave = t >> 6;
  int lane = t & 63;
  int arow = wave * 16 + (lane & 15);
  int kgrp = (lane >> 4) * 8;

  bf16x8 afrag[4];
#pragma unroll
  for (int ks = 0; ks < 4; ++ks) {
    int kb = ks * 32 + kgrp;
    int byte = (arow * 256 + kb * 2) ^ ((arow & 7) << 4);
    afrag[ks] = *reinterpret_cast<const bf16x8*>(xt + byte);
  }

  f32x4 acc[9];
#pragma unroll
  for (int ct = 0; ct < 9; ++ct) {
    f32x4 a = {0.f, 0.f, 0.f, 0.f};
#pragma unroll
    for (int ks = 0; ks < 4; ++ks) {
      bf16x8 b = *reinterpret_cast<const bf16x8*>(&WF[(size_t)((ct * 4 + ks) * 64 + lane) * 8]);
      a = __builtin_amdgcn_mfma_f32_16x16x32_bf16(afrag[ks], b, a, 0, 0, 0);
    }
    acc[ct] = a;
  }

  int rbase = wave * 16 + (lane >> 4) * 4;
  int csub = lane & 15;
#pragma unroll
  for (int ct = 0; ct < 8; ++ct) {
#pragma unroll
    for (int i = 0; i < 4; ++i) {
      int gr = row0 + rbase + i;
      if (gr < n)
        XSH[(size_t)ct * n * 16 + (size_t)gr * 16 + csub] = (ushort)f2bf(acc[ct][i]);
    }
  }
#pragma unroll
  for (int i = 0; i < 4; ++i) {
    int gr = row0 + rbase + i;
    if (gr < n) {
      float v = acc[8][i];
      if (csub < 8) ALS[(size_t)gr * 8 + csub] = v;
      else ALD[(size_t)gr * 8 + (csub - 8)] = v;
    }
  }
}

// ============================ pass W: per-edge weights, head-major fp16 ============================
// wave per node; lane: e4 = lane>>2 (edge slot), cq = lane&3 (head pair cq*2, cq*2+1)
__global__ __launch_bounds__(256) void k_passw(const float* __restrict__ ALS,
                                               const float* __restrict__ ALD,
                                               const int* __restrict__ rowptr,
                                               const int* __restrict__ col,
                                               ushort* __restrict__ w8h, int n, int E) {
  int t = threadIdx.x;
  int lane = t & 63;
  int node = blockIdx.x * 4 + (t >> 6);
  if (node >= n) return;
  int e4 = lane >> 2, cq = lane & 3;
  float2 ad = *reinterpret_cast<const float2*>(ALD + (size_t)node * 8 + cq * 2);
  int beg = __builtin_nontemporal_load(rowptr + node);
  int end = __builtin_nontemporal_load(rowptr + node + 1);
  for (int base = beg; base < end; base += 32) {
    int i0 = base + e4, i1 = base + 16 + e4;
    bool on0 = i0 < end, on1 = i1 < end;
    int ci0 = on0 ? i0 : beg, ci1 = on1 ? i1 : beg;
    int s0 = __builtin_nontemporal_load(col + ci0);
    int s1 = __builtin_nontemporal_load(col + ci1);
    float2 as0 = *reinterpret_cast<const float2*>(ALS + (size_t)s0 * 8 + cq * 2);
    float2 as1 = *reinterpret_cast<const float2*>(ALS + (size_t)s1 * 8 + cq * 2);
    if (on0) {
      ushort u0 = f2h(__expf(lrelu(as0.x + ad.x, LEAKY_ATT)));
      ushort u1 = f2h(__expf(lrelu(as0.y + ad.y, LEAKY_ATT)));
      __builtin_nontemporal_store(u0, w8h + (size_t)(cq * 2) * E + i0);
      __builtin_nontemporal_store(u1, w8h + (size_t)(cq * 2 + 1) * E + i0);
    }
    if (on1) {
      ushort u0 = f2h(__expf(lrelu(as1.x + ad.x, LEAKY_ATT)));
      ushort u1 = f2h(__expf(lrelu(as1.y + ad.y, LEAKY_ATT)));
      __builtin_nontemporal_store(u0, w8h + (size_t)(cq * 2) * E + i1);
      __builtin_nontemporal_store(u1, w8h + (size_t)(cq * 2 + 1) * E + i1);
    }
  }
}

// ============================ sliced aggregation: slice = head = blockIdx&7 (XCD-bound) ==========
// wave per node per slice. lane: e4 = lane>>2 (edge slot 0..15), cq = lane&3 (channel quad).
// Inner loop: col (nt stream) + w (nt stream) + XSH 32B gather (L2-resident slice, ~3.2MB).
__global__ __launch_bounds__(256) void k_aggs(const ushort* __restrict__ XSH,
                                              const ushort* __restrict__ w8h,
                                              const float* __restrict__ ALS,
                                              const float* __restrict__ ALD,
                                              const int* __restrict__ rowptr,
                                              const int* __restrict__ col,
                                              const float* __restrict__ bias,
                                              ushort* __restrict__ HB, int n, int E) {
  int t = threadIdx.x;
  int lane = t & 63;
  int bid = blockIdx.x;
  int h = bid & 7;
  int node = (bid >> 3) * 4 + (t >> 6);
  if (node >= n) return;
  int e4 = lane >> 2, cq = lane & 3;
  const char* XHb = (const char*)XSH + (size_t)h * n * 32;
  const ushort* wz = w8h + (size_t)h * E;

  // self loop
  float w0 = __expf(lrelu(ALS[(size_t)node * 8 + h] + ALD[(size_t)node * 8 + h], LEAKY_ATT));
  float sw = (e4 == 0) ? w0 : 0.f;
  uint2 qs = *(const uint2*)(XHb + ((uint)node * 32 + cq * 8));
  float a0 = sw * bf_lo(qs.x), a1 = sw * bf_hi(qs.x);
  float a2 = sw * bf_lo(qs.y), a3 = sw * bf_hi(qs.y);
  float den = sw;

  int beg = __builtin_nontemporal_load(rowptr + node);
  int end = __builtin_nontemporal_load(rowptr + node + 1);
  for (int base = beg; base < end; base += 32) {
    int i0 = base + e4, i1 = base + 16 + e4;
    bool on0 = i0 < end, on1 = i1 < end;
    int ci0 = on0 ? i0 : beg, ci1 = on1 ? i1 : beg;
    int s0 = __builtin_nontemporal_load(col + ci0);
    int s1 = __builtin_nontemporal_load(col + ci1);
    ushort uw0 = __builtin_nontemporal_load(wz + ci0);
    ushort uw1 = __builtin_nontemporal_load(wz + ci1);
    uint2 q0 = *(const uint2*)(XHb + ((uint)s0 * 32 + cq * 8));
    uint2 q1 = *(const uint2*)(XHb + ((uint)s1 * 32 + cq * 8));
    float wA = on0 ? h2f(uw0) : 0.f;
    float wB = on1 ? h2f(uw1) : 0.f;
    a0 += wA * bf_lo(q0.x);
    a1 += wA * bf_hi(q0.x);
    a2 += wA * bf_lo(q0.y);
    a3 += wA * bf_hi(q0.y);
    a0 += wB * bf_lo(q1.x);
    a1 += wB * bf_hi(q1.x);
    a2 += wB * bf_lo(q1.y);
    a3 += wB * bf_hi(q1.y);
    den += wA + wB;
  }

#pragma unroll
  for (int m = 4; m <= 32; m <<= 1) {
    a0 += __shfl_xor(a0, m);
    a1 += __shfl_xor(a1, m);
    a2 += __shfl_xor(a2, m);
    a3 += __shfl_xor(a3, m);
    den += __shfl_xor(den, m);
  }

  if (lane < 4) {
    int ch0 = h * 16 + lane * 4;
    float inv = 1.f / den;
    float4 bv = *reinterpret_cast<const float4*>(&bias[ch0]);
    float r0 = lrelu(a0 * inv + bv.x, LEAKY_ACT);
    float r1 = lrelu(a1 * inv + bv.y, LEAKY_ACT);
    float r2 = lrelu(a2 * inv + bv.z, LEAKY_ACT);
    float r3 = lrelu(a3 * inv + bv.w, LEAKY_ACT);
    unsigned long long o =
        (unsigned long long)(f2bf(r0) | (f2bf(r1) << 16)) |
        ((unsigned long long)(f2bf(r2) | (f2bf(r3) << 16)) << 32);
    __builtin_nontemporal_store(
        o, reinterpret_cast<unsigned long long*>(&HB[(size_t)node * 128 + ch0]));
  }
}

// ============================ lin3: xsal3 = HB @ U ============================
// 32 lanes per node; lane reads 4 ch (uint2 bf16), 8 nodes per 256-thr block
__global__ __launch_bounds__(256) void k_lin3b(const ushort* __restrict__ HB,
                                               const float* __restrict__ U,
                                               float* __restrict__ X3, int n) {
  int t = threadIdx.x;
  int node = blockIdx.x * 8 + (t >> 5);
  if (node >= n) return;
  int sub = t & 31;
  uint2 q = *reinterpret_cast<const uint2*>(&HB[(size_t)node * 128 + sub * 4]);
  float r0 = bf_lo(q.x), r1 = bf_hi(q.x), r2 = bf_lo(q.y), r3 = bf_hi(q.y);
  int c0 = sub * 4;
  float4 u0 = *reinterpret_cast<const float4*>(&U[(c0 + 0) * 4]);
  float4 u1 = *reinterpret_cast<const float4*>(&U[(c0 + 1) * 4]);
  float4 u2 = *reinterpret_cast<const float4*>(&U[(c0 + 2) * 4]);
  float4 u3 = *reinterpret_cast<const float4*>(&U[(c0 + 3) * 4]);
  float p0 = r0 * u0.x + r1 * u1.x + r2 * u2.x + r3 * u3.x;
  float p1 = r0 * u0.y + r1 * u1.y + r2 * u2.y + r3 * u3.y;
  float p2 = r0 * u0.z + r1 * u1.z + r2 * u2.z + r3 * u3.z;
  float p3 = r0 * u0.w + r1 * u1.w + r2 * u2.w + r3 * u3.w;
#pragma unroll
  for (int m = 1; m <= 16; m <<= 1) {
    p0 += __shfl_xor(p0, m);
    p1 += __shfl_xor(p1, m);
    p2 += __shfl_xor(p2, m);
    p3 += __shfl_xor(p3, m);
  }
  if (sub == 0)
    *reinterpret_cast<float4*>(&X3[(size_t)node * 4]) = make_float4(p0, p1, p2, p3);
}

// ============================ layer 3 aggregation ============================
__global__ __launch_bounds__(256) void k_agg3(const float* __restrict__ XSAL3,
                                              const int* __restrict__ rowptr,
                                              const int* __restrict__ col,
                                              const float* __restrict__ b3,
                                              float* __restrict__ out, int n) {
  int node = blockIdx.x * blockDim.x + threadIdx.x;
  if (node >= n) return;
  const char* XB = (const char*)XSAL3;
  float4 self = *(const float4*)(XB + ((size_t)((uint)node << 4)));
  float ald = self.w;
  float w0 = __expf(lrelu(self.z + ald, LEAKY_ATT));
  float den = w0;
  float a0 = w0 * self.x;
  float a1 = w0 * self.y;
  int jj = rowptr[node], end = rowptr[node + 1];
  for (; jj + 4 <= end; jj += 4) {
    int sA = __builtin_nontemporal_load(col + jj);
    int sB = __builtin_nontemporal_load(col + jj + 1);
    int sC = __builtin_nontemporal_load(col + jj + 2);
    int sD = __builtin_nontemporal_load(col + jj + 3);
    float4 vA = *(const float4*)(XB + ((uint)sA << 4));
    float4 vB = *(const float4*)(XB + ((uint)sB << 4));
    float4 vC = *(const float4*)(XB + ((uint)sC << 4));
    float4 vD = *(const float4*)(XB + ((uint)sD << 4));
    float wA = __expf(lrelu(vA.z + ald, LEAKY_ATT));
    float wB = __expf(lrelu(vB.z + ald, LEAKY_ATT));
    float wC = __expf(lrelu(vC.z + ald, LEAKY_ATT));
    float wD = __expf(lrelu(vD.z + ald, LEAKY_ATT));
    a0 += wA * vA.x + wB * vB.x + wC * vC.x + wD * vD.x;
    a1 += wA * vA.y + wB * vB.y + wC * vC.y + wD * vD.y;
    den += (wA + wB) + (wC + wD);
  }
  for (; jj < end; ++jj) {
    int s = __builtin_nontemporal_load(col + jj);
    float4 v = *(const float4*)(XB + ((uint)s << 4));
    float w = __expf(lrelu(v.z + ald, LEAKY_ATT));
    den += w;
    a0 += w * v.x;
    a1 += w * v.y;
  }
  out[node * 2 + 0] = a0 / den + b3[0];
  out[node * 2 + 1] = a1 / den + b3[1];
}

// ============================ launch ============================
extern "C" void kernel_launch(void* const* d_in, const int* in_sizes, int n_in,
                              void* d_out, int out_size, void* d_ws, size_t ws_size,
                              hipStream_t stream) {
  const float* x = (const float*)d_in[0];
  const int* ei = (const int*)d_in[1];
  const float* w1s = (const float*)d_in[2];
  const float* w1d = (const float*)d_in[3];
  const float* a1s = (const float*)d_in[4];
  const float* a1d = (const float*)d_in[5];
  const float* b1 = (const float*)d_in[6];
  const float* w2s = (const float*)d_in[7];
  const float* w2d = (const float*)d_in[8];
  const float* a2s = (const float*)d_in[9];
  const float* a2d = (const float*)d_in[10];
  const float* b2 = (const float*)d_in[11];
  const float* w3s = (const float*)d_in[12];
  const float* w3d = (const float*)d_in[13];
  const float* a3s = (const float*)d_in[14];
  const float* a3d = (const float*)d_in[15];
  const float* b3 = (const float*)d_in[16];

  int n = in_sizes[0] / 128;
  int e = in_sizes[1] / 2;
  const int* srcp = ei;
  const int* dstp = ei + e;

  int nb = (n + 255) >> BSHIFT;
  if (nb > 512) return;
  if (n >= (1 << 20)) return;

  size_t off = 0;
  auto alloc = [&](size_t bytes) -> void* {
    void* p = (char*)d_ws + off;
    off += (bytes + 255) & ~(size_t)255;
    return p;
  };
  int* bcnt = (int*)alloc((size_t)nb * 4);
  int* bbase = (int*)alloc((size_t)(nb + 1) * 4);
  int* bcur = (int*)alloc((size_t)nb * 4);
  // w8h (8 heads x E fp16) also serves as bpair scratch (bpair dead before w8h written)
  size_t w8h_bytes = (size_t)8 * e * 2;
  size_t bpair_bytes = (size_t)e * 4;
  ushort* w8h = (ushort*)alloc(w8h_bytes > bpair_bytes ? w8h_bytes : bpair_bytes);
  uint* bpair = (uint*)w8h;
  int* rowptr = (int*)alloc((size_t)(n + 1) * 4);
  int* col = (int*)alloc((size_t)e * 4);
  float* vsd1 = (float*)alloc(128 * 16 * 4);
  float* vsd2 = (float*)alloc(128 * 16 * 4);
  float* u3 = (float*)alloc(128 * 4 * 4);
  ushort* wf1 = (ushort*)alloc(36 * 64 * 8 * 2);
  ushort* wf2 = (ushort*)alloc(36 * 64 * 8 * 2);
  float* als8 = (float*)alloc((size_t)n * 8 * 4);
  float* ald8 = (float*)alloc((size_t)n * 8 * 4);
  ushort* xsh = (ushort*)alloc((size_t)n * 128 * 2);
  ushort* hb = (ushort*)alloc((size_t)n * 128 * 2);
  float* xsal3 = (float*)alloc((size_t)n * 4 * 4);
  if (off > ws_size) return;

  // CSR build
  (void)hipMemsetAsync(bcnt, 0, (size_t)nb * 4, stream);
  k_bhist<<<512, 256, 0, stream>>>(dstp, e, nb, bcnt);
  k_bscan<<<1, 512, 0, stream>>>(bcnt, nb, bbase, bcur);
  k_bucket<<<(e + CH - 1) / CH, 256, 0, stream>>>(srcp, dstp, e, nb, bcur, bpair);
  k_csr<<<nb, 256, 0, stream>>>(bpair, bbase, n, rowptr, col);

  // weight prep
  k_prep_vsd<<<128, 16, 0, stream>>>(w1s, w1d, a1s, a1d, vsd1);
  k_prep_vsd<<<128, 16, 0, stream>>>(w2s, w2d, a2s, a2d, vsd2);
  k_prep_u3<<<1, 128, 0, stream>>>(w3s, w3d, a3s, a3d, u3);
  k_prep_frag<<<36, 64, 0, stream>>>(w1s, vsd1, wf1);
  k_prep_frag<<<36, 64, 0, stream>>>(w2s, vsd2, wf2);

  int gb = (n + 63) / 64;
  int pb = (n + 3) / 4;        // passw blocks (4 nodes/block)
  int ab = ((n + 3) / 4) * 8;  // aggs blocks (4 nodes/block x 8 slices)

  // layer 1
  k_gemm_mfma<0><<<gb, 256, 0, stream>>>(x, wf1, xsh, als8, ald8, n);
  k_passw<<<pb, 256, 0, stream>>>(als8, ald8, rowptr, col, w8h, n, e);
  k_aggs<<<ab, 256, 0, stream>>>(xsh, w8h, als8, ald8, rowptr, col, b1, hb, n, e);
  // layer 2
  k_gemm_mfma<1><<<gb, 256, 0, stream>>>(hb, wf2, xsh, als8, ald8, n);
  k_passw<<<pb, 256, 0, stream>>>(als8, ald8, rowptr, col, w8h, n, e);
  k_aggs<<<ab, 256, 0, stream>>>(xsh, w8h, als8, ald8, rowptr, col, b2, hb, n, e);
  // layer 3
  k_lin3b<<<(n + 7) / 8, 256, 0, stream>>>(hb, u3, xsal3, n);
  k_agg3<<<(n + 255) / 256, 256, 0, stream>>>(xsal3, rowptr, col, b3, (float*)d_out, n);
}

// Round 11
// 583.660 us; speedup vs baseline: 1.3797x; 1.3797x over previous
//
#include <hip/hip_runtime.h>
#include <hip/hip_bf16.h>

#define LEAKY_ATT 0.2f
#define LEAKY_ACT 0.01f
#define BSHIFT 8
#define CH 4096

typedef __attribute__((ext_vector_type(8))) short bf16x8;
typedef __attribute__((ext_vector_type(4))) float f32x4;

__device__ __forceinline__ float lrelu(float x, float s) { return fmaxf(x, s * x); }

__device__ __forceinline__ uint f2bf(float f) {
  __hip_bfloat16 h = __float2bfloat16(f);  // RTNE
  return (uint)*reinterpret_cast<ushort*>(&h);
}

__device__ __forceinline__ float bf_lo(uint q) { return __uint_as_float(q << 16); }
__device__ __forceinline__ float bf_hi(uint q) { return __uint_as_float(q & 0xffff0000u); }

__device__ __forceinline__ void acc16(float* acc, uint4 qa, uint4 qb, float w) {
  acc[0] += w * bf_lo(qa.x);
  acc[1] += w * bf_hi(qa.x);
  acc[2] += w * bf_lo(qa.y);
  acc[3] += w * bf_hi(qa.y);
  acc[4] += w * bf_lo(qa.z);
  acc[5] += w * bf_hi(qa.z);
  acc[6] += w * bf_lo(qa.w);
  acc[7] += w * bf_hi(qa.w);
  acc[8] += w * bf_lo(qb.x);
  acc[9] += w * bf_hi(qb.x);
  acc[10] += w * bf_lo(qb.y);
  acc[11] += w * bf_hi(qb.y);
  acc[12] += w * bf_lo(qb.z);
  acc[13] += w * bf_hi(qb.z);
  acc[14] += w * bf_lo(qb.w);
  acc[15] += w * bf_hi(qb.w);
}

// ============================ CSR build: two-level counting sort ============================
__global__ __launch_bounds__(256) void k_bhist(const int* __restrict__ dst, int e, int nb,
                                               int* __restrict__ bcnt) {
  __shared__ int cnt[512];
  for (int i = threadIdx.x; i < 512; i += 256) cnt[i] = 0;
  __syncthreads();
  for (int i = blockIdx.x * 256 + threadIdx.x; i < e; i += gridDim.x * 256)
    atomicAdd(&cnt[dst[i] >> BSHIFT], 1);
  __syncthreads();
  for (int i = threadIdx.x; i < nb; i += 256)
    if (cnt[i]) atomicAdd(&bcnt[i], cnt[i]);
}

__global__ __launch_bounds__(512) void k_bscan(const int* __restrict__ bcnt, int nb,
                                               int* __restrict__ bbase, int* __restrict__ bcur) {
  __shared__ int sh[512];
  int t = threadIdx.x;
  int orig = (t < nb) ? bcnt[t] : 0;
  sh[t] = orig;
  __syncthreads();
  for (int off = 1; off < 512; off <<= 1) {
    int v = (t >= off) ? sh[t - off] : 0;
    __syncthreads();
    sh[t] += v;
    __syncthreads();
  }
  if (t < nb) {
    int ex = sh[t] - orig;
    bbase[t] = ex;
    bcur[t] = ex;
    if (t == nb - 1) bbase[nb] = sh[t];
  }
}

__global__ __launch_bounds__(256) void k_bucket(const int* __restrict__ src,
                                                const int* __restrict__ dst, int e, int nb,
                                                int* __restrict__ bcur, uint* __restrict__ bpair) {
  __shared__ uint spair[CH];
  __shared__ ushort skey[CH];
  __shared__ ushort srank[CH];
  __shared__ int cnt[512];
  __shared__ int gb[512];
  int t = threadIdx.x;
  int c0 = blockIdx.x * CH;
  int cn = min(CH, e - c0);
  if (cn <= 0) return;
  for (int i = t; i < 512; i += 256) cnt[i] = 0;
  __syncthreads();
  for (int i = t; i < cn; i += 256) {
    int s = src[c0 + i];
    int d = dst[c0 + i];
    int k = d >> BSHIFT;
    spair[i] = ((uint)(d & ((1 << BSHIFT) - 1)) << 20) | (uint)s;
    skey[i] = (ushort)k;
    srank[i] = (ushort)atomicAdd(&cnt[k], 1);
  }
  __syncthreads();
  for (int k = t; k < nb; k += 256)
    gb[k] = cnt[k] ? atomicAdd(&bcur[k], cnt[k]) : 0;
  __syncthreads();
  for (int i = t; i < cn; i += 256) {
    bpair[gb[skey[i]] + srank[i]] = spair[i];
  }
}

__global__ __launch_bounds__(256) void k_csr(const uint* __restrict__ bpair,
                                             const int* __restrict__ bbase, int n,
                                             int* __restrict__ rowptr, int* __restrict__ col) {
  __shared__ int deg[256];
  __shared__ int cur[256];
  int b = blockIdx.x, t = threadIdx.x;
  int e0 = bbase[b], e1 = bbase[b + 1];
  deg[t] = 0;
  __syncthreads();
  for (int i = e0 + t; i < e1; i += 256)
    atomicAdd(&deg[bpair[i] >> 20], 1);
  __syncthreads();
  int v = deg[t];
  cur[t] = v;
  __syncthreads();
  for (int off = 1; off < 256; off <<= 1) {
    int u = (t >= off) ? cur[t - off] : 0;
    __syncthreads();
    cur[t] += u;
    __syncthreads();
  }
  int incl = cur[t];
  int gnode = b * 256 + t;
  if (gnode < n) rowptr[gnode + 1] = e0 + incl;
  if (b == 0 && t == 0) rowptr[0] = 0;
  __syncthreads();
  cur[t] = e0 + incl - v;
  __syncthreads();
  for (int i = e0 + t; i < e1; i += 256) {
    uint pk = bpair[i];
    int loc = pk >> 20;
    int p = atomicAdd(&cur[loc], 1);
    col[p] = (int)(pk & 0xFFFFFu);
  }
}

// ============================ weight prep ============================
__global__ void k_prep_vsd(const float* __restrict__ wsrc, const float* __restrict__ wdst,
                           const float* __restrict__ asrc, const float* __restrict__ adst,
                           float* __restrict__ vsd) {
  int k = blockIdx.x;
  int i = threadIdx.x;
  float s = 0.f;
  if (i < 8) {
    for (int c = 0; c < 16; ++c) s += wsrc[k * 128 + i * 16 + c] * asrc[i * 16 + c];
  } else {
    int h = i - 8;
    for (int c = 0; c < 16; ++c) s += wdst[k * 128 + h * 16 + c] * adst[h * 16 + c];
  }
  vsd[k * 16 + i] = s;
}

__global__ void k_prep_u3(const float* __restrict__ w3s, const float* __restrict__ w3d,
                          const float* __restrict__ a3s, const float* __restrict__ a3d,
                          float* __restrict__ U) {
  int k = blockIdx.x * blockDim.x + threadIdx.x;
  if (k >= 128) return;
  U[k * 4 + 0] = w3s[k * 2 + 0];
  U[k * 4 + 1] = w3s[k * 2 + 1];
  U[k * 4 + 2] = w3s[k * 2 + 0] * a3s[0] + w3s[k * 2 + 1] * a3s[1];
  U[k * 4 + 3] = w3d[k * 2 + 0] * a3d[0] + w3d[k * 2 + 1] * a3d[1];
}

// B-fragment pre-swizzle (see R6 notes)
__global__ __launch_bounds__(64) void k_prep_frag(const float* __restrict__ W,
                                                  const float* __restrict__ VSD,
                                                  ushort* __restrict__ WF) {
  int blk = blockIdx.x;  // ct*4+ks, 36 blocks
  int lane = threadIdx.x;
  int ct = blk >> 2, ks = blk & 3;
  uint out[4];
#pragma unroll
  for (int jj = 0; jj < 8; ++jj) {
    int k = ks * 32 + (lane >> 4) * 8 + jj;
    int c = ct * 16 + (lane & 15);
    float v = (c < 128) ? W[k * 128 + c] : VSD[k * 16 + (c - 128)];
    ((ushort*)out)[jj] = (ushort)f2bf(v);
  }
  *reinterpret_cast<uint4*>(&WF[(size_t)(blk * 64 + lane) * 8]) = *reinterpret_cast<uint4*>(out);
}

// ============================ MFMA GEMM: [XSH | ALSH/ALDH] = Xtile @ [W | VSD] ============================
// XSH head-major: XSH[h][node][16] bf16. ALSH/ALDH head-major: [h][node] f32.
template <int INMODE>  // 0: fp32 X, 1: bf16 X
__global__ __launch_bounds__(256) void k_gemm_mfma(const void* __restrict__ Xv,
                                                   const ushort* __restrict__ WF,
                                                   ushort* __restrict__ XSH,
                                                   float* __restrict__ ALSH,
                                                   float* __restrict__ ALDH, int n) {
  __shared__ __align__(16) char xt[16384];  // 64 rows x 128 k bf16
  int t = threadIdx.x;
  int row0 = blockIdx.x * 64;

  if (INMODE == 0) {
    const float* X = (const float*)Xv;
#pragma unroll
    for (int i = 0; i < 8; ++i) {
      int flat = (i * 256 + t) * 4;
      int r = flat >> 7, k0 = flat & 127;
      int gr = row0 + r;
      float4 v = (gr < n) ? *reinterpret_cast<const float4*>(&X[(size_t)gr * 128 + k0])
                          : make_float4(0.f, 0.f, 0.f, 0.f);
      uint lo = f2bf(v.x) | (f2bf(v.y) << 16);
      uint hi = f2bf(v.z) | (f2bf(v.w) << 16);
      int byte = (r * 256 + k0 * 2) ^ ((r & 7) << 4);
      *reinterpret_cast<uint2*>(xt + byte) = make_uint2(lo, hi);
    }
  } else {
    const ushort* X = (const ushort*)Xv;
#pragma unroll
    for (int i = 0; i < 4; ++i) {
      int flat = (i * 256 + t) * 8;
      int r = flat >> 7, k0 = flat & 127;
      int gr = row0 + r;
      uint4 v = (gr < n) ? *reinterpret_cast<const uint4*>(&X[(size_t)gr * 128 + k0])
                         : make_uint4(0u, 0u, 0u, 0u);
      int byte = (r * 256 + k0 * 2) ^ ((r & 7) << 4);
      *reinterpret_cast<uint4*>(xt + byte) = v;
    }
  }
  __syncthreads();

  int wave = t >> 6;
  int lane = t & 63;
  int arow = wave * 16 + (lane & 15);
  int kgrp = (lane >> 4) * 8;

  bf16x8 afrag[4];
#pragma unroll
  for (int ks = 0; ks < 4; ++ks) {
    int kb = ks * 32 + kgrp;
    int byte = (arow * 256 + kb * 2) ^ ((arow & 7) << 4);
    afrag[ks] = *reinterpret_cast<const bf16x8*>(xt + byte);
  }

  f32x4 acc[9];
#pragma unroll
  for (int ct = 0; ct < 9; ++ct) {
    f32x4 a = {0.f, 0.f, 0.f, 0.f};
#pragma unroll
    for (int ks = 0; ks < 4; ++ks) {
      bf16x8 b = *reinterpret_cast<const bf16x8*>(&WF[(size_t)((ct * 4 + ks) * 64 + lane) * 8]);
      a = __builtin_amdgcn_mfma_f32_16x16x32_bf16(afrag[ks], b, a, 0, 0, 0);
    }
    acc[ct] = a;
  }

  int rbase = wave * 16 + (lane >> 4) * 4;
  int csub = lane & 15;
#pragma unroll
  for (int ct = 0; ct < 8; ++ct) {
#pragma unroll
    for (int i = 0; i < 4; ++i) {
      int gr = row0 + rbase + i;
      if (gr < n)
        XSH[(size_t)ct * n * 16 + (size_t)gr * 16 + csub] = (ushort)f2bf(acc[ct][i]);
    }
  }
#pragma unroll
  for (int i = 0; i < 4; ++i) {
    int gr = row0 + rbase + i;
    if (gr < n) {
      float v = acc[8][i];
      if (csub < 8) ALSH[(size_t)csub * n + gr] = v;
      else ALDH[(size_t)(csub - 8) * n + gr] = v;
    }
  }
}

// ============================ sliced aggregation: thread-per-(node,head) ============================
// slice h = blockIdx&7 (XCD-affine; XSH slice ~3.2MB + ALSH slice 400KB stay L2-resident).
// Thread owns all 16 channels of (node,h): serial edge walk, 4-unrolled, no shuffles/barriers.
__global__ __launch_bounds__(256) void k_aggs(const ushort* __restrict__ XSH,
                                              const float* __restrict__ ALSH,
                                              const float* __restrict__ ALDH,
                                              const int* __restrict__ rowptr,
                                              const int* __restrict__ col,
                                              const float* __restrict__ bias,
                                              ushort* __restrict__ HB, int n) {
  int bid = blockIdx.x;
  int h = bid & 7;
  int node = (bid >> 3) * 256 + threadIdx.x;
  if (node >= n) return;
  const ushort* XH = XSH + (size_t)h * n * 16;
  const float* als = ALSH + (size_t)h * n;
  float ald = ALDH[(size_t)h * n + node];

  float acc[16];
  float den;
  {
    float w0 = __expf(lrelu(als[node] + ald, LEAKY_ATT));
    const uint4* p = (const uint4*)(XH + (size_t)node * 16);
    uint4 qa = p[0], qb = p[1];
#pragma unroll
    for (int c = 0; c < 16; ++c) acc[c] = 0.f;
    acc16(acc, qa, qb, w0);
    den = w0;
  }

  int j = rowptr[node];
  int end = rowptr[node + 1];
  for (; j + 4 <= end; j += 4) {
    int s0 = __builtin_nontemporal_load(col + j + 0);
    int s1 = __builtin_nontemporal_load(col + j + 1);
    int s2 = __builtin_nontemporal_load(col + j + 2);
    int s3 = __builtin_nontemporal_load(col + j + 3);
    float l0 = als[s0];
    float l1 = als[s1];
    float l2 = als[s2];
    float l3 = als[s3];
    const uint4* p0 = (const uint4*)(XH + (size_t)s0 * 16);
    const uint4* p1 = (const uint4*)(XH + (size_t)s1 * 16);
    const uint4* p2 = (const uint4*)(XH + (size_t)s2 * 16);
    const uint4* p3 = (const uint4*)(XH + (size_t)s3 * 16);
    uint4 qa0 = p0[0], qb0 = p0[1];
    uint4 qa1 = p1[0], qb1 = p1[1];
    uint4 qa2 = p2[0], qb2 = p2[1];
    uint4 qa3 = p3[0], qb3 = p3[1];
    float w0 = __expf(lrelu(l0 + ald, LEAKY_ATT));
    float w1 = __expf(lrelu(l1 + ald, LEAKY_ATT));
    float w2 = __expf(lrelu(l2 + ald, LEAKY_ATT));
    float w3 = __expf(lrelu(l3 + ald, LEAKY_ATT));
    acc16(acc, qa0, qb0, w0);
    acc16(acc, qa1, qb1, w1);
    acc16(acc, qa2, qb2, w2);
    acc16(acc, qa3, qb3, w3);
    den += (w0 + w1) + (w2 + w3);
  }
  for (; j < end; ++j) {
    int s = __builtin_nontemporal_load(col + j);
    float l = als[s];
    const uint4* p = (const uint4*)(XH + (size_t)s * 16);
    uint4 qa = p[0], qb = p[1];
    float w = __expf(lrelu(l + ald, LEAKY_ATT));
    acc16(acc, qa, qb, w);
    den += w;
  }

  float inv = 1.f / den;
  const float* bp = bias + h * 16;
  ushort* outp = HB + (size_t)node * 128 + h * 16;
#pragma unroll
  for (int g = 0; g < 4; ++g) {
    float r0 = lrelu(acc[g * 4 + 0] * inv + bp[g * 4 + 0], LEAKY_ACT);
    float r1 = lrelu(acc[g * 4 + 1] * inv + bp[g * 4 + 1], LEAKY_ACT);
    float r2 = lrelu(acc[g * 4 + 2] * inv + bp[g * 4 + 2], LEAKY_ACT);
    float r3 = lrelu(acc[g * 4 + 3] * inv + bp[g * 4 + 3], LEAKY_ACT);
    unsigned long long o =
        (unsigned long long)(f2bf(r0) | (f2bf(r1) << 16)) |
        ((unsigned long long)(f2bf(r2) | (f2bf(r3) << 16)) << 32);
    __builtin_nontemporal_store(o, reinterpret_cast<unsigned long long*>(outp + g * 4));
  }
}

// ============================ lin3: xsal3 = HB @ U ============================
__global__ __launch_bounds__(256) void k_lin3b(const ushort* __restrict__ HB,
                                               const float* __restrict__ U,
                                               float* __restrict__ X3, int n) {
  int t = threadIdx.x;
  int node = blockIdx.x * 8 + (t >> 5);
  if (node >= n) return;
  int sub = t & 31;
  uint2 q = *reinterpret_cast<const uint2*>(&HB[(size_t)node * 128 + sub * 4]);
  float r0 = bf_lo(q.x), r1 = bf_hi(q.x), r2 = bf_lo(q.y), r3 = bf_hi(q.y);
  int c0 = sub * 4;
  float4 u0 = *reinterpret_cast<const float4*>(&U[(c0 + 0) * 4]);
  float4 u1 = *reinterpret_cast<const float4*>(&U[(c0 + 1) * 4]);
  float4 u2 = *reinterpret_cast<const float4*>(&U[(c0 + 2) * 4]);
  float4 u3 = *reinterpret_cast<const float4*>(&U[(c0 + 3) * 4]);
  float p0 = r0 * u0.x + r1 * u1.x + r2 * u2.x + r3 * u3.x;
  float p1 = r0 * u0.y + r1 * u1.y + r2 * u2.y + r3 * u3.y;
  float p2 = r0 * u0.z + r1 * u1.z + r2 * u2.z + r3 * u3.z;
  float p3 = r0 * u0.w + r1 * u1.w + r2 * u2.w + r3 * u3.w;
#pragma unroll
  for (int m = 1; m <= 16; m <<= 1) {
    p0 += __shfl_xor(p0, m);
    p1 += __shfl_xor(p1, m);
    p2 += __shfl_xor(p2, m);
    p3 += __shfl_xor(p3, m);
  }
  if (sub == 0)
    *reinterpret_cast<float4*>(&X3[(size_t)node * 4]) = make_float4(p0, p1, p2, p3);
}

// ============================ layer 3 aggregation ============================
__global__ __launch_bounds__(256) void k_agg3(const float* __restrict__ XSAL3,
                                              const int* __restrict__ rowptr,
                                              const int* __restrict__ col,
                                              const float* __restrict__ b3,
                                              float* __restrict__ out, int n) {
  int node = blockIdx.x * blockDim.x + threadIdx.x;
  if (node >= n) return;
  const char* XB = (const char*)XSAL3;
  float4 self = *(const float4*)(XB + ((size_t)((uint)node << 4)));
  float ald = self.w;
  float w0 = __expf(lrelu(self.z + ald, LEAKY_ATT));
  float den = w0;
  float a0 = w0 * self.x;
  float a1 = w0 * self.y;
  int jj = rowptr[node], end = rowptr[node + 1];
  for (; jj + 4 <= end; jj += 4) {
    int sA = __builtin_nontemporal_load(col + jj);
    int sB = __builtin_nontemporal_load(col + jj + 1);
    int sC = __builtin_nontemporal_load(col + jj + 2);
    int sD = __builtin_nontemporal_load(col + jj + 3);
    float4 vA = *(const float4*)(XB + ((uint)sA << 4));
    float4 vB = *(const float4*)(XB + ((uint)sB << 4));
    float4 vC = *(const float4*)(XB + ((uint)sC << 4));
    float4 vD = *(const float4*)(XB + ((uint)sD << 4));
    float wA = __expf(lrelu(vA.z + ald, LEAKY_ATT));
    float wB = __expf(lrelu(vB.z + ald, LEAKY_ATT));
    float wC = __expf(lrelu(vC.z + ald, LEAKY_ATT));
    float wD = __expf(lrelu(vD.z + ald, LEAKY_ATT));
    a0 += wA * vA.x + wB * vB.x + wC * vC.x + wD * vD.x;
    a1 += wA * vA.y + wB * vB.y + wC * vC.y + wD * vD.y;
    den += (wA + wB) + (wC + wD);
  }
  for (; jj < end; ++jj) {
    int s = __builtin_nontemporal_load(col + jj);
    float4 v = *(const float4*)(XB + ((uint)s << 4));
    float w = __expf(lrelu(v.z + ald, LEAKY_ATT));
    den += w;
    a0 += w * v.x;
    a1 += w * v.y;
  }
  out[node * 2 + 0] = a0 / den + b3[0];
  out[node * 2 + 1] = a1 / den + b3[1];
}

// ============================ launch ============================
extern "C" void kernel_launch(void* const* d_in, const int* in_sizes, int n_in,
                              void* d_out, int out_size, void* d_ws, size_t ws_size,
                              hipStream_t stream) {
  const float* x = (const float*)d_in[0];
  const int* ei = (const int*)d_in[1];
  const float* w1s = (const float*)d_in[2];
  const float* w1d = (const float*)d_in[3];
  const float* a1s = (const float*)d_in[4];
  const float* a1d = (const float*)d_in[5];
  const float* b1 = (const float*)d_in[6];
  const float* w2s = (const float*)d_in[7];
  const float* w2d = (const float*)d_in[8];
  const float* a2s = (const float*)d_in[9];
  const float* a2d = (const float*)d_in[10];
  const float* b2 = (const float*)d_in[11];
  const float* w3s = (const float*)d_in[12];
  const float* w3d = (const float*)d_in[13];
  const float* a3s = (const float*)d_in[14];
  const float* a3d = (const float*)d_in[15];
  const float* b3 = (const float*)d_in[16];

  int n = in_sizes[0] / 128;
  int e = in_sizes[1] / 2;
  const int* srcp = ei;
  const int* dstp = ei + e;

  int nb = (n + 255) >> BSHIFT;
  if (nb > 512) return;
  if (n >= (1 << 20)) return;

  size_t off = 0;
  auto alloc = [&](size_t bytes) -> void* {
    void* p = (char*)d_ws + off;
    off += (bytes + 255) & ~(size_t)255;
    return p;
  };
  int* bcnt = (int*)alloc((size_t)nb * 4);
  int* bbase = (int*)alloc((size_t)(nb + 1) * 4);
  int* bcur = (int*)alloc((size_t)nb * 4);
  uint* bpair = (uint*)alloc((size_t)e * 4);
  int* rowptr = (int*)alloc((size_t)(n + 1) * 4);
  int* col = (int*)alloc((size_t)e * 4);
  float* vsd1 = (float*)alloc(128 * 16 * 4);
  float* vsd2 = (float*)alloc(128 * 16 * 4);
  float* u3 = (float*)alloc(128 * 4 * 4);
  ushort* wf1 = (ushort*)alloc(36 * 64 * 8 * 2);
  ushort* wf2 = (ushort*)alloc(36 * 64 * 8 * 2);
  float* alsh = (float*)alloc((size_t)n * 8 * 4);
  float* aldh = (float*)alloc((size_t)n * 8 * 4);
  ushort* xsh = (ushort*)alloc((size_t)n * 128 * 2);
  ushort* hb = (ushort*)alloc((size_t)n * 128 * 2);
  float* xsal3 = (float*)alloc((size_t)n * 4 * 4);
  if (off > ws_size) return;

  // CSR build
  (void)hipMemsetAsync(bcnt, 0, (size_t)nb * 4, stream);
  k_bhist<<<512, 256, 0, stream>>>(dstp, e, nb, bcnt);
  k_bscan<<<1, 512, 0, stream>>>(bcnt, nb, bbase, bcur);
  k_bucket<<<(e + CH - 1) / CH, 256, 0, stream>>>(srcp, dstp, e, nb, bcur, bpair);
  k_csr<<<nb, 256, 0, stream>>>(bpair, bbase, n, rowptr, col);

  // weight prep
  k_prep_vsd<<<128, 16, 0, stream>>>(w1s, w1d, a1s, a1d, vsd1);
  k_prep_vsd<<<128, 16, 0, stream>>>(w2s, w2d, a2s, a2d, vsd2);
  k_prep_u3<<<1, 128, 0, stream>>>(w3s, w3d, a3s, a3d, u3);
  k_prep_frag<<<36, 64, 0, stream>>>(w1s, vsd1, wf1);
  k_prep_frag<<<36, 64, 0, stream>>>(w2s, vsd2, wf2);

  int gb = (n + 63) / 64;
  int ab = ((n + 255) / 256) * 8;  // 8 head slices x node chunks of 256

  // layer 1
  k_gemm_mfma<0><<<gb, 256, 0, stream>>>(x, wf1, xsh, alsh, aldh, n);
  k_aggs<<<ab, 256, 0, stream>>>(xsh, alsh, aldh, rowptr, col, b1, hb, n);
  // layer 2
  k_gemm_mfma<1><<<gb, 256, 0, stream>>>(hb, wf2, xsh, alsh, aldh, n);
  k_aggs<<<ab, 256, 0, stream>>>(xsh, alsh, aldh, rowptr, col, b2, hb, n);
  // layer 3
  k_lin3b<<<(n + 7) / 8, 256, 0, stream>>>(hb, u3, xsal3, n);
  k_agg3<<<(n + 255) / 256, 256, 0, stream>>>(xsal3, rowptr, col, b3, (float*)d_out, n);
}

// Round 12
// 302.130 us; speedup vs baseline: 2.6654x; 1.9318x over previous
//
#include <hip/hip_runtime.h>
#include <hip/hip_bf16.h>

#define LEAKY_ATT 0.2f
#define LEAKY_ACT 0.01f
#define BSHIFT 8
#define CH 4096

typedef __attribute__((ext_vector_type(8))) short bf16x8;
typedef __attribute__((ext_vector_type(4))) float f32x4;

__device__ __forceinline__ float lrelu(float x, float s) { return fmaxf(x, s * x); }

__device__ __forceinline__ uint f2bf(float f) {
  __hip_bfloat16 h = __float2bfloat16(f);  // RTNE
  return (uint)*reinterpret_cast<ushort*>(&h);
}

__device__ __forceinline__ float bf_lo(uint q) { return __uint_as_float(q << 16); }
__device__ __forceinline__ float bf_hi(uint q) { return __uint_as_float(q & 0xffff0000u); }

// ============================ CSR build: two-level counting sort ============================
__global__ __launch_bounds__(256) void k_bhist(const int* __restrict__ dst, int e, int nb,
                                               int* __restrict__ bcnt) {
  __shared__ int cnt[512];
  for (int i = threadIdx.x; i < 512; i += 256) cnt[i] = 0;
  __syncthreads();
  for (int i = blockIdx.x * 256 + threadIdx.x; i < e; i += gridDim.x * 256)
    atomicAdd(&cnt[dst[i] >> BSHIFT], 1);
  __syncthreads();
  for (int i = threadIdx.x; i < nb; i += 256)
    if (cnt[i]) atomicAdd(&bcnt[i], cnt[i]);
}

__global__ __launch_bounds__(512) void k_bscan(const int* __restrict__ bcnt, int nb,
                                               int* __restrict__ bbase, int* __restrict__ bcur) {
  __shared__ int sh[512];
  int t = threadIdx.x;
  int orig = (t < nb) ? bcnt[t] : 0;
  sh[t] = orig;
  __syncthreads();
  for (int off = 1; off < 512; off <<= 1) {
    int v = (t >= off) ? sh[t - off] : 0;
    __syncthreads();
    sh[t] += v;
    __syncthreads();
  }
  if (t < nb) {
    int ex = sh[t] - orig;
    bbase[t] = ex;
    bcur[t] = ex;
    if (t == nb - 1) bbase[nb] = sh[t];
  }
}

__global__ __launch_bounds__(256) void k_bucket(const int* __restrict__ src,
                                                const int* __restrict__ dst, int e, int nb,
                                                int* __restrict__ bcur, uint* __restrict__ bpair) {
  __shared__ uint spair[CH];
  __shared__ ushort skey[CH];
  __shared__ ushort srank[CH];
  __shared__ int cnt[512];
  __shared__ int gb[512];
  int t = threadIdx.x;
  int c0 = blockIdx.x * CH;
  int cn = min(CH, e - c0);
  if (cn <= 0) return;
  for (int i = t; i < 512; i += 256) cnt[i] = 0;
  __syncthreads();
  for (int i = t; i < cn; i += 256) {
    int s = src[c0 + i];
    int d = dst[c0 + i];
    int k = d >> BSHIFT;
    spair[i] = ((uint)(d & ((1 << BSHIFT) - 1)) << 20) | (uint)s;
    skey[i] = (ushort)k;
    srank[i] = (ushort)atomicAdd(&cnt[k], 1);
  }
  __syncthreads();
  for (int k = t; k < nb; k += 256)
    gb[k] = cnt[k] ? atomicAdd(&bcur[k], cnt[k]) : 0;
  __syncthreads();
  for (int i = t; i < cn; i += 256) {
    bpair[gb[skey[i]] + srank[i]] = spair[i];
  }
}

__global__ __launch_bounds__(256) void k_csr(const uint* __restrict__ bpair,
                                             const int* __restrict__ bbase, int n,
                                             int* __restrict__ rowptr, int* __restrict__ col) {
  __shared__ int deg[256];
  __shared__ int cur[256];
  int b = blockIdx.x, t = threadIdx.x;
  int e0 = bbase[b], e1 = bbase[b + 1];
  deg[t] = 0;
  __syncthreads();
  for (int i = e0 + t; i < e1; i += 256)
    atomicAdd(&deg[bpair[i] >> 20], 1);
  __syncthreads();
  int v = deg[t];
  cur[t] = v;
  __syncthreads();
  for (int off = 1; off < 256; off <<= 1) {
    int u = (t >= off) ? cur[t - off] : 0;
    __syncthreads();
    cur[t] += u;
    __syncthreads();
  }
  int incl = cur[t];
  int gnode = b * 256 + t;
  if (gnode < n) rowptr[gnode + 1] = e0 + incl;
  if (b == 0 && t == 0) rowptr[0] = 0;
  __syncthreads();
  cur[t] = e0 + incl - v;
  __syncthreads();
  for (int i = e0 + t; i < e1; i += 256) {
    uint pk = bpair[i];
    int loc = pk >> 20;
    int p = atomicAdd(&cur[loc], 1);
    col[p] = (int)(pk & 0xFFFFFu);
  }
}

// ============================ weight prep ============================
__global__ void k_prep_vsd(const float* __restrict__ wsrc, const float* __restrict__ wdst,
                           const float* __restrict__ asrc, const float* __restrict__ adst,
                           float* __restrict__ vsd) {
  int k = blockIdx.x;
  int i = threadIdx.x;
  float s = 0.f;
  if (i < 8) {
    for (int c = 0; c < 16; ++c) s += wsrc[k * 128 + i * 16 + c] * asrc[i * 16 + c];
  } else {
    int h = i - 8;
    for (int c = 0; c < 16; ++c) s += wdst[k * 128 + h * 16 + c] * adst[h * 16 + c];
  }
  vsd[k * 16 + i] = s;
}

__global__ void k_prep_u3(const float* __restrict__ w3s, const float* __restrict__ w3d,
                          const float* __restrict__ a3s, const float* __restrict__ a3d,
                          float* __restrict__ U) {
  int k = blockIdx.x * blockDim.x + threadIdx.x;
  if (k >= 128) return;
  U[k * 4 + 0] = w3s[k * 2 + 0];
  U[k * 4 + 1] = w3s[k * 2 + 1];
  U[k * 4 + 2] = w3s[k * 2 + 0] * a3s[0] + w3s[k * 2 + 1] * a3s[1];
  U[k * 4 + 3] = w3d[k * 2 + 0] * a3d[0] + w3d[k * 2 + 1] * a3d[1];
}

// B-fragment pre-swizzle (see R6 notes)
__global__ __launch_bounds__(64) void k_prep_frag(const float* __restrict__ W,
                                                  const float* __restrict__ VSD,
                                                  ushort* __restrict__ WF) {
  int blk = blockIdx.x;  // ct*4+ks, 36 blocks
  int lane = threadIdx.x;
  int ct = blk >> 2, ks = blk & 3;
  uint out[4];
#pragma unroll
  for (int jj = 0; jj < 8; ++jj) {
    int k = ks * 32 + (lane >> 4) * 8 + jj;
    int c = ct * 16 + (lane & 15);
    float v = (c < 128) ? W[k * 128 + c] : VSD[k * 16 + (c - 128)];
    ((ushort*)out)[jj] = (ushort)f2bf(v);
  }
  *reinterpret_cast<uint4*>(&WF[(size_t)(blk * 64 + lane) * 8]) = *reinterpret_cast<uint4*>(out);
}

// ============================ MFMA GEMM: [XSb | AL] = Xtile @ [W | VSD] ============================
template <int INMODE>  // 0: fp32 X, 1: bf16 X
__global__ __launch_bounds__(256) void k_gemm_mfma(const void* __restrict__ Xv,
                                                   const ushort* __restrict__ WF,
                                                   ushort* __restrict__ XSb,
                                                   float* __restrict__ AL, int n) {
  __shared__ __align__(16) char xt[16384];  // 64 rows x 128 k bf16
  int t = threadIdx.x;
  int row0 = blockIdx.x * 64;

  if (INMODE == 0) {
    const float* X = (const float*)Xv;
#pragma unroll
    for (int i = 0; i < 8; ++i) {
      int flat = (i * 256 + t) * 4;
      int r = flat >> 7, k0 = flat & 127;
      int gr = row0 + r;
      float4 v = (gr < n) ? *reinterpret_cast<const float4*>(&X[(size_t)gr * 128 + k0])
                          : make_float4(0.f, 0.f, 0.f, 0.f);
      uint lo = f2bf(v.x) | (f2bf(v.y) << 16);
      uint hi = f2bf(v.z) | (f2bf(v.w) << 16);
      int byte = (r * 256 + k0 * 2) ^ ((r & 7) << 4);
      *reinterpret_cast<uint2*>(xt + byte) = make_uint2(lo, hi);
    }
  } else {
    const ushort* X = (const ushort*)Xv;
#pragma unroll
    for (int i = 0; i < 4; ++i) {
      int flat = (i * 256 + t) * 8;
      int r = flat >> 7, k0 = flat & 127;
      int gr = row0 + r;
      uint4 v = (gr < n) ? *reinterpret_cast<const uint4*>(&X[(size_t)gr * 128 + k0])
                         : make_uint4(0u, 0u, 0u, 0u);
      int byte = (r * 256 + k0 * 2) ^ ((r & 7) << 4);
      *reinterpret_cast<uint4*>(xt + byte) = v;
    }
  }
  __syncthreads();

  int wave = t >> 6;
  int lane = t & 63;
  int arow = wave * 16 + (lane & 15);
  int kgrp = (lane >> 4) * 8;

  bf16x8 afrag[4];
#pragma unroll
  for (int ks = 0; ks < 4; ++ks) {
    int kb = ks * 32 + kgrp;
    int byte = (arow * 256 + kb * 2) ^ ((arow & 7) << 4);
    afrag[ks] = *reinterpret_cast<const bf16x8*>(xt + byte);
  }

  f32x4 acc[9];
#pragma unroll
  for (int ct = 0; ct < 9; ++ct) {
    f32x4 a = {0.f, 0.f, 0.f, 0.f};
#pragma unroll
    for (int ks = 0; ks < 4; ++ks) {
      bf16x8 b = *reinterpret_cast<const bf16x8*>(&WF[(size_t)((ct * 4 + ks) * 64 + lane) * 8]);
      a = __builtin_amdgcn_mfma_f32_16x16x32_bf16(afrag[ks], b, a, 0, 0, 0);
    }
    acc[ct] = a;
  }

  int rbase = wave * 16 + (lane >> 4) * 4;
  int csub = lane & 15;
#pragma unroll
  for (int ct = 0; ct < 8; ++ct) {
#pragma unroll
    for (int i = 0; i < 4; ++i) {
      int gr = row0 + rbase + i;
      if (gr < n) XSb[(size_t)gr * 128 + ct * 16 + csub] = (ushort)f2bf(acc[ct][i]);
    }
  }
#pragma unroll
  for (int i = 0; i < 4; ++i) {
    int gr = row0 + rbase + i;
    if (gr < n) AL[(size_t)gr * 16 + csub] = acc[8][i];
  }
}

// ============================ layer 1/2 aggregation: wave-per-node, 16-deep MLP ============================
// lane: g = lane>>5 (edge parity), sub = lane&31 (channel quad c0=4*sub, head hd=sub>>2).
// Main loop: 16 edges per iter (8 per group) -> 24 independent loads in flight per lane.
// MODE 1: write bf16 activations HB. MODE 2: fused lin3 -> XSAL3[n][4] (needs U).
template <int MODE>
__global__ __launch_bounds__(256) void k_gat_agg(const ushort* __restrict__ XSb,
                                                 const float* __restrict__ AL,
                                                 const int* __restrict__ rowptr,
                                                 const int* __restrict__ col,
                                                 const float* __restrict__ bias,
                                                 void* __restrict__ OUTv,
                                                 const float* __restrict__ U, int n) {
  int t = threadIdx.x;
  int lane = t & 63;
  int node = blockIdx.x * 4 + (t >> 6);
  if (node >= n) return;
  int sub = lane & 31;
  int g = lane >> 5;
  int hd = sub >> 2;
  uint xsub = (uint)(sub * 8);  // byte offset in 256B row
  uint hd4 = (uint)(hd * 4);    // byte offset in 64B AL row
  const char* XB = (const char*)XSb;
  const char* AB = (const char*)AL;

  float ald = *(const float*)(AB + (((uint)node << 6) + 32u + hd4));

  // self loop (group 0 only)
  float w0 = __expf(lrelu(*(const float*)(AB + (((uint)node << 6) + hd4)) + ald, LEAKY_ATT));
  if (g != 0) w0 = 0.f;
  uint2 qs = *(const uint2*)(XB + (((uint)node << 8) + xsub));
  float acc0 = w0 * bf_lo(qs.x);
  float acc1 = w0 * bf_hi(qs.x);
  float acc2 = w0 * bf_lo(qs.y);
  float acc3 = w0 * bf_hi(qs.y);
  float den = w0;

  int beg = rowptr[node], end = rowptr[node + 1];
  int base = beg;
  // main: 16 edges per iter (8 per group) — 24 independent loads in flight
  for (; base + 16 <= end; base += 16) {
    int s0 = col[base + g];
    int s1 = col[base + 2 + g];
    int s2 = col[base + 4 + g];
    int s3 = col[base + 6 + g];
    int s4 = col[base + 8 + g];
    int s5 = col[base + 10 + g];
    int s6 = col[base + 12 + g];
    int s7 = col[base + 14 + g];
    float l0 = *(const float*)(AB + (((uint)s0 << 6) + hd4));
    float l1 = *(const float*)(AB + (((uint)s1 << 6) + hd4));
    float l2 = *(const float*)(AB + (((uint)s2 << 6) + hd4));
    float l3 = *(const float*)(AB + (((uint)s3 << 6) + hd4));
    float l4 = *(const float*)(AB + (((uint)s4 << 6) + hd4));
    float l5 = *(const float*)(AB + (((uint)s5 << 6) + hd4));
    float l6 = *(const float*)(AB + (((uint)s6 << 6) + hd4));
    float l7 = *(const float*)(AB + (((uint)s7 << 6) + hd4));
    uint2 q0 = *(const uint2*)(XB + (((uint)s0 << 8) + xsub));
    uint2 q1 = *(const uint2*)(XB + (((uint)s1 << 8) + xsub));
    uint2 q2 = *(const uint2*)(XB + (((uint)s2 << 8) + xsub));
    uint2 q3 = *(const uint2*)(XB + (((uint)s3 << 8) + xsub));
    uint2 q4 = *(const uint2*)(XB + (((uint)s4 << 8) + xsub));
    uint2 q5 = *(const uint2*)(XB + (((uint)s5 << 8) + xsub));
    uint2 q6 = *(const uint2*)(XB + (((uint)s6 << 8) + xsub));
    uint2 q7 = *(const uint2*)(XB + (((uint)s7 << 8) + xsub));
    float wa = __expf(lrelu(l0 + ald, LEAKY_ATT));
    float wb = __expf(lrelu(l1 + ald, LEAKY_ATT));
    float wc = __expf(lrelu(l2 + ald, LEAKY_ATT));
    float wd = __expf(lrelu(l3 + ald, LEAKY_ATT));
    float we = __expf(lrelu(l4 + ald, LEAKY_ATT));
    float wf = __expf(lrelu(l5 + ald, LEAKY_ATT));
    float wg = __expf(lrelu(l6 + ald, LEAKY_ATT));
    float wh = __expf(lrelu(l7 + ald, LEAKY_ATT));
    acc0 += wa * bf_lo(q0.x);
    acc1 += wa * bf_hi(q0.x);
    acc2 += wa * bf_lo(q0.y);
    acc3 += wa * bf_hi(q0.y);
    acc0 += wb * bf_lo(q1.x);
    acc1 += wb * bf_hi(q1.x);
    acc2 += wb * bf_lo(q1.y);
    acc3 += wb * bf_hi(q1.y);
    acc0 += wc * bf_lo(q2.x);
    acc1 += wc * bf_hi(q2.x);
    acc2 += wc * bf_lo(q2.y);
    acc3 += wc * bf_hi(q2.y);
    acc0 += wd * bf_lo(q3.x);
    acc1 += wd * bf_hi(q3.x);
    acc2 += wd * bf_lo(q3.y);
    acc3 += wd * bf_hi(q3.y);
    acc0 += we * bf_lo(q4.x);
    acc1 += we * bf_hi(q4.x);
    acc2 += we * bf_lo(q4.y);
    acc3 += we * bf_hi(q4.y);
    acc0 += wf * bf_lo(q5.x);
    acc1 += wf * bf_hi(q5.x);
    acc2 += wf * bf_lo(q5.y);
    acc3 += wf * bf_hi(q5.y);
    acc0 += wg * bf_lo(q6.x);
    acc1 += wg * bf_hi(q6.x);
    acc2 += wg * bf_lo(q6.y);
    acc3 += wg * bf_hi(q6.y);
    acc0 += wh * bf_lo(q7.x);
    acc1 += wh * bf_hi(q7.x);
    acc2 += wh * bf_lo(q7.y);
    acc3 += wh * bf_hi(q7.y);
    den += ((wa + wb) + (wc + wd)) + ((we + wf) + (wg + wh));
  }
  // 8-edge step
  if (base + 8 <= end) {
    int s0 = col[base + g];
    int s1 = col[base + 2 + g];
    int s2 = col[base + 4 + g];
    int s3 = col[base + 6 + g];
    float l0 = *(const float*)(AB + (((uint)s0 << 6) + hd4));
    float l1 = *(const float*)(AB + (((uint)s1 << 6) + hd4));
    float l2 = *(const float*)(AB + (((uint)s2 << 6) + hd4));
    float l3 = *(const float*)(AB + (((uint)s3 << 6) + hd4));
    uint2 q0 = *(const uint2*)(XB + (((uint)s0 << 8) + xsub));
    uint2 q1 = *(const uint2*)(XB + (((uint)s1 << 8) + xsub));
    uint2 q2 = *(const uint2*)(XB + (((uint)s2 << 8) + xsub));
    uint2 q3 = *(const uint2*)(XB + (((uint)s3 << 8) + xsub));
    float wa = __expf(lrelu(l0 + ald, LEAKY_ATT));
    float wb = __expf(lrelu(l1 + ald, LEAKY_ATT));
    float wc = __expf(lrelu(l2 + ald, LEAKY_ATT));
    float wd = __expf(lrelu(l3 + ald, LEAKY_ATT));
    acc0 += wa * bf_lo(q0.x);
    acc1 += wa * bf_hi(q0.x);
    acc2 += wa * bf_lo(q0.y);
    acc3 += wa * bf_hi(q0.y);
    acc0 += wb * bf_lo(q1.x);
    acc1 += wb * bf_hi(q1.x);
    acc2 += wb * bf_lo(q1.y);
    acc3 += wb * bf_hi(q1.y);
    acc0 += wc * bf_lo(q2.x);
    acc1 += wc * bf_hi(q2.x);
    acc2 += wc * bf_lo(q2.y);
    acc3 += wc * bf_hi(q2.y);
    acc0 += wd * bf_lo(q3.x);
    acc1 += wd * bf_hi(q3.x);
    acc2 += wd * bf_lo(q3.y);
    acc3 += wd * bf_hi(q3.y);
    den += (wa + wb) + (wc + wd);
    base += 8;
  }
  // 4-edge step
  if (base + 4 <= end) {
    int s0 = col[base + g];
    int s1 = col[base + 2 + g];
    float l0 = *(const float*)(AB + (((uint)s0 << 6) + hd4));
    float l1 = *(const float*)(AB + (((uint)s1 << 6) + hd4));
    uint2 q0 = *(const uint2*)(XB + (((uint)s0 << 8) + xsub));
    uint2 q1 = *(const uint2*)(XB + (((uint)s1 << 8) + xsub));
    float wa = __expf(lrelu(l0 + ald, LEAKY_ATT));
    float wb = __expf(lrelu(l1 + ald, LEAKY_ATT));
    acc0 += wa * bf_lo(q0.x);
    acc1 += wa * bf_hi(q0.x);
    acc2 += wa * bf_lo(q0.y);
    acc3 += wa * bf_hi(q0.y);
    acc0 += wb * bf_lo(q1.x);
    acc1 += wb * bf_hi(q1.x);
    acc2 += wb * bf_lo(q1.y);
    acc3 += wb * bf_hi(q1.y);
    den += wa + wb;
    base += 4;
  }
  // masked remainder (0-3 edges), 2 at a time
  for (; base < end; base += 2) {
    int idx = base + g;
    bool on = idx < end;
    int s = on ? col[idx] : node;
    float l = *(const float*)(AB + (((uint)s << 6) + hd4));
    uint2 q = *(const uint2*)(XB + (((uint)s << 8) + xsub));
    float w = on ? __expf(lrelu(l + ald, LEAKY_ATT)) : 0.f;
    acc0 += w * bf_lo(q.x);
    acc1 += w * bf_hi(q.x);
    acc2 += w * bf_lo(q.y);
    acc3 += w * bf_hi(q.y);
    den += w;
  }

  acc0 += __shfl_xor(acc0, 32);
  acc1 += __shfl_xor(acc1, 32);
  acc2 += __shfl_xor(acc2, 32);
  acc3 += __shfl_xor(acc3, 32);
  den += __shfl_xor(den, 32);

  if (g == 0) {
    int c0 = sub * 4;
    float inv = 1.f / den;
    float4 bv = *reinterpret_cast<const float4*>(&bias[c0]);
    float r0 = lrelu(acc0 * inv + bv.x, LEAKY_ACT);
    float r1 = lrelu(acc1 * inv + bv.y, LEAKY_ACT);
    float r2 = lrelu(acc2 * inv + bv.z, LEAKY_ACT);
    float r3 = lrelu(acc3 * inv + bv.w, LEAKY_ACT);
    if (MODE == 1) {
      ushort* HB = (ushort*)OUTv;
      uint lo = f2bf(r0) | (f2bf(r1) << 16);
      uint hi = f2bf(r2) | (f2bf(r3) << 16);
      *reinterpret_cast<uint2*>(&HB[(size_t)node * 128 + c0]) = make_uint2(lo, hi);
    } else {
      float rr[4] = {r0, r1, r2, r3};
      float p0 = 0.f, p1 = 0.f, p2 = 0.f, p3 = 0.f;
#pragma unroll
      for (int c = 0; c < 4; ++c) {
        float4 uv = *reinterpret_cast<const float4*>(&U[(c0 + c) * 4]);
        p0 += rr[c] * uv.x;
        p1 += rr[c] * uv.y;
        p2 += rr[c] * uv.z;
        p3 += rr[c] * uv.w;
      }
#pragma unroll
      for (int m = 1; m < 32; m <<= 1) {
        p0 += __shfl_xor(p0, m);
        p1 += __shfl_xor(p1, m);
        p2 += __shfl_xor(p2, m);
        p3 += __shfl_xor(p3, m);
      }
      if (sub == 0) {
        float* X3 = (float*)OUTv;
        *reinterpret_cast<float4*>(&X3[(size_t)node * 4]) = make_float4(p0, p1, p2, p3);
      }
    }
  }
}

// ============================ layer 3 aggregation: 8 edges in flight ============================
__global__ __launch_bounds__(256) void k_agg3(const float* __restrict__ XSAL3,
                                              const int* __restrict__ rowptr,
                                              const int* __restrict__ col,
                                              const float* __restrict__ b3,
                                              float* __restrict__ out, int n) {
  int node = blockIdx.x * blockDim.x + threadIdx.x;
  if (node >= n) return;
  const char* XB = (const char*)XSAL3;
  float4 self = *(const float4*)(XB + ((size_t)((uint)node << 4)));
  float ald = self.w;
  float w0 = __expf(lrelu(self.z + ald, LEAKY_ATT));
  float den = w0;
  float a0 = w0 * self.x;
  float a1 = w0 * self.y;
  int jj = rowptr[node], end = rowptr[node + 1];
  for (; jj + 8 <= end; jj += 8) {
    int sA = __builtin_nontemporal_load(col + jj);
    int sB = __builtin_nontemporal_load(col + jj + 1);
    int sC = __builtin_nontemporal_load(col + jj + 2);
    int sD = __builtin_nontemporal_load(col + jj + 3);
    int sE = __builtin_nontemporal_load(col + jj + 4);
    int sF = __builtin_nontemporal_load(col + jj + 5);
    int sG = __builtin_nontemporal_load(col + jj + 6);
    int sH = __builtin_nontemporal_load(col + jj + 7);
    float4 vA = *(const float4*)(XB + ((uint)sA << 4));
    float4 vB = *(const float4*)(XB + ((uint)sB << 4));
    float4 vC = *(const float4*)(XB + ((uint)sC << 4));
    float4 vD = *(const float4*)(XB + ((uint)sD << 4));
    float4 vE = *(const float4*)(XB + ((uint)sE << 4));
    float4 vF = *(const float4*)(XB + ((uint)sF << 4));
    float4 vG = *(const float4*)(XB + ((uint)sG << 4));
    float4 vH = *(const float4*)(XB + ((uint)sH << 4));
    float wA = __expf(lrelu(vA.z + ald, LEAKY_ATT));
    float wB = __expf(lrelu(vB.z + ald, LEAKY_ATT));
    float wC = __expf(lrelu(vC.z + ald, LEAKY_ATT));
    float wD = __expf(lrelu(vD.z + ald, LEAKY_ATT));
    float wE = __expf(lrelu(vE.z + ald, LEAKY_ATT));
    float wF = __expf(lrelu(vF.z + ald, LEAKY_ATT));
    float wG = __expf(lrelu(vG.z + ald, LEAKY_ATT));
    float wH = __expf(lrelu(vH.z + ald, LEAKY_ATT));
    a0 += wA * vA.x + wB * vB.x + wC * vC.x + wD * vD.x;
    a1 += wA * vA.y + wB * vB.y + wC * vC.y + wD * vD.y;
    a0 += wE * vE.x + wF * vF.x + wG * vG.x + wH * vH.x;
    a1 += wE * vE.y + wF * vF.y + wG * vG.y + wH * vH.y;
    den += ((wA + wB) + (wC + wD)) + ((wE + wF) + (wG + wH));
  }
  for (; jj + 4 <= end; jj += 4) {
    int sA = __builtin_nontemporal_load(col + jj);
    int sB = __builtin_nontemporal_load(col + jj + 1);
    int sC = __builtin_nontemporal_load(col + jj + 2);
    int sD = __builtin_nontemporal_load(col + jj + 3);
    float4 vA = *(const float4*)(XB + ((uint)sA << 4));
    float4 vB = *(const float4*)(XB + ((uint)sB << 4));
    float4 vC = *(const float4*)(XB + ((uint)sC << 4));
    float4 vD = *(const float4*)(XB + ((uint)sD << 4));
    float wA = __expf(lrelu(vA.z + ald, LEAKY_ATT));
    float wB = __expf(lrelu(vB.z + ald, LEAKY_ATT));
    float wC = __expf(lrelu(vC.z + ald, LEAKY_ATT));
    float wD = __expf(lrelu(vD.z + ald, LEAKY_ATT));
    a0 += wA * vA.x + wB * vB.x + wC * vC.x + wD * vD.x;
    a1 += wA * vA.y + wB * vB.y + wC * vC.y + wD * vD.y;
    den += (wA + wB) + (wC + wD);
  }
  for (; jj < end; ++jj) {
    int s = __builtin_nontemporal_load(col + jj);
    float4 v = *(const float4*)(XB + ((uint)s << 4));
    float w = __expf(lrelu(v.z + ald, LEAKY_ATT));
    den += w;
    a0 += w * v.x;
    a1 += w * v.y;
  }
  out[node * 2 + 0] = a0 / den + b3[0];
  out[node * 2 + 1] = a1 / den + b3[1];
}

// ============================ launch ============================
extern "C" void kernel_launch(void* const* d_in, const int* in_sizes, int n_in,
                              void* d_out, int out_size, void* d_ws, size_t ws_size,
                              hipStream_t stream) {
  const float* x = (const float*)d_in[0];
  const int* ei = (const int*)d_in[1];
  const float* w1s = (const float*)d_in[2];
  const float* w1d = (const float*)d_in[3];
  const float* a1s = (const float*)d_in[4];
  const float* a1d = (const float*)d_in[5];
  const float* b1 = (const float*)d_in[6];
  const float* w2s = (const float*)d_in[7];
  const float* w2d = (const float*)d_in[8];
  const float* a2s = (const float*)d_in[9];
  const float* a2d = (const float*)d_in[10];
  const float* b2 = (const float*)d_in[11];
  const float* w3s = (const float*)d_in[12];
  const float* w3d = (const float*)d_in[13];
  const float* a3s = (const float*)d_in[14];
  const float* a3d = (const float*)d_in[15];
  const float* b3 = (const float*)d_in[16];

  int n = in_sizes[0] / 128;
  int e = in_sizes[1] / 2;
  const int* srcp = ei;
  const int* dstp = ei + e;

  int nb = (n + 255) >> BSHIFT;
  if (nb > 512) return;
  if (n >= (1 << 20)) return;

  size_t off = 0;
  auto alloc = [&](size_t bytes) -> void* {
    void* p = (char*)d_ws + off;
    off += (bytes + 255) & ~(size_t)255;
    return p;
  };
  int* bcnt = (int*)alloc((size_t)nb * 4);
  int* bbase = (int*)alloc((size_t)(nb + 1) * 4);
  int* bcur = (int*)alloc((size_t)nb * 4);
  uint* bpair = (uint*)alloc((size_t)e * 4);
  int* rowptr = (int*)alloc((size_t)(n + 1) * 4);
  int* col = (int*)alloc((size_t)e * 4);
  float* vsd1 = (float*)alloc(128 * 16 * 4);
  float* vsd2 = (float*)alloc(128 * 16 * 4);
  float* u3 = (float*)alloc(128 * 4 * 4);
  ushort* wf1 = (ushort*)alloc(36 * 64 * 8 * 2);
  ushort* wf2 = (ushort*)alloc(36 * 64 * 8 * 2);
  float* al = (float*)alloc((size_t)n * 16 * 4);
  ushort* xsb = (ushort*)alloc((size_t)n * 128 * 2);
  ushort* hb = (ushort*)alloc((size_t)n * 128 * 2);
  float* xsal3 = (float*)alloc((size_t)n * 4 * 4);
  if (off > ws_size) return;

  // CSR build
  (void)hipMemsetAsync(bcnt, 0, (size_t)nb * 4, stream);
  k_bhist<<<512, 256, 0, stream>>>(dstp, e, nb, bcnt);
  k_bscan<<<1, 512, 0, stream>>>(bcnt, nb, bbase, bcur);
  k_bucket<<<(e + CH - 1) / CH, 256, 0, stream>>>(srcp, dstp, e, nb, bcur, bpair);
  k_csr<<<nb, 256, 0, stream>>>(bpair, bbase, n, rowptr, col);

  // weight prep
  k_prep_vsd<<<128, 16, 0, stream>>>(w1s, w1d, a1s, a1d, vsd1);
  k_prep_vsd<<<128, 16, 0, stream>>>(w2s, w2d, a2s, a2d, vsd2);
  k_prep_u3<<<1, 128, 0, stream>>>(w3s, w3d, a3s, a3d, u3);
  k_prep_frag<<<36, 64, 0, stream>>>(w1s, vsd1, wf1);
  k_prep_frag<<<36, 64, 0, stream>>>(w2s, vsd2, wf2);

  int gb = (n + 63) / 64;
  int ab = (n + 3) / 4;
  // layer 1
  k_gemm_mfma<0><<<gb, 256, 0, stream>>>(x, wf1, xsb, al, n);
  k_gat_agg<1><<<ab, 256, 0, stream>>>(xsb, al, rowptr, col, b1, hb, nullptr, n);
  // layer 2 (+fused lin3)
  k_gemm_mfma<1><<<gb, 256, 0, stream>>>(hb, wf2, xsb, al, n);
  k_gat_agg<2><<<ab, 256, 0, stream>>>(xsb, al, rowptr, col, b2, xsal3, u3, n);
  // layer 3
  k_agg3<<<(n + 255) / 256, 256, 0, stream>>>(xsal3, rowptr, col, b3, (float*)d_out, n);
}